// Round 21
// baseline (540.683 us; speedup 1.0000x reference)
//
#include <hip/hip_runtime.h>
#include <hip/hip_bf16.h>

#define B_SZ     32
#define IN_DIM   1024
#define K_TOTAL  525824          // = 8216 * 64
#define OUT_DIM  512
#define NCH64    8216            // 64-k chunks
#define KSEG     64              // k-segments
#define P_BYTES  ((size_t)KSEG * B_SZ * OUT_DIM * 4)  // 4.2 MB partials
#define XT_BYTES ((size_t)IN_DIM * B_SZ * 4)          // 128 KB transposed x
#define NEED_WS  (P_BYTES + XT_BYTES)

typedef __attribute__((ext_vector_type(8))) short bfrag;   // 8 bf16 = 4 VGPR
typedef __attribute__((ext_vector_type(4))) float f32x4;

// async global->LDS, 16B per lane; LDS dest = wave-uniform base + lane*16,
// global source address is PER-LANE (swizzle goes on the source).
#define GLD16(g, l) __builtin_amdgcn_global_load_lds(                      \
    (const __attribute__((address_space(1))) void*)(g),                    \
    (__attribute__((address_space(3))) void*)(l), 16, 0, 0)

// fp32 -> bf16 round-to-nearest-even (pure integer)
__device__ inline unsigned bf16r(float f)
{
    unsigned u = __builtin_bit_cast(unsigned, f);
    return (u + 0x7FFFu + ((u >> 16) & 1u)) >> 16;
}
__device__ inline unsigned pk2(float a, float b)
{
    return bf16r(a) | (bf16r(b) << 16);
}

// ---------------------------------------------------------------- bias init (fallback path only)
__global__ void bias_init_kernel(const float* __restrict__ bias, float* __restrict__ out)
{
    int i = blockIdx.x * 256 + threadIdx.x;     // 16384 total
    out[i] = bias[i & (OUT_DIM - 1)];
}

// ------------- kernel A: transpose x -> xT[k][b] (128 KB, L2-resident)
__global__ __launch_bounds__(256)
void xpose_kernel(const float* __restrict__ x, float* __restrict__ xT)
{
    const int idx = blockIdx.x * 256 + threadIdx.x;   // 0..32767
    const int k = idx >> 5, b = idx & 31;
    xT[idx] = x[b * IN_DIM + k];                      // write coalesced
}

// ------------- kernel B: BARRIER-FREE wave-private MFMA GEMM.
// Each wave: 16 o-rows x one k-segment; private LDS (W 2x4KB swz + f 2x4KB);
// per period: wait vmcnt(4) -> COMPUTE(64k) -> FCOMP(t+2) -> WSTAGE(t+2).
// No s_barrier anywhere: the probe-verified free-running DMA rhythm.
__global__ __launch_bounds__(256, 2)
void qgemm_mfma_kernel(const float* __restrict__ xT,
                       const float* __restrict__ W,
                       float* __restrict__ partial)
{
    __shared__ int4 wbuf[4][2][16][16];          // 32 KB: per-wave W (swizzled rows)
    __shared__ int4 fbuf[4][2][256];             // 32 KB: per-wave f fragments

    const int tid  = threadIdx.x;
    const int lane = tid & 63;
    const int wv_  = tid >> 6;                   // 0..3
    const int lrow = lane & 15;                  // o-row within tile / A row
    const int lkb  = lane >> 4;                  // k-octet group 0..3

    const int gw   = blockIdx.x * 4 + wv_;       // 0..2047
    const int og   = gw >> 6;                    // 0..31
    const int kseg = gw & 63;                    // 0..63

    const int o_base = og * 16;

    f32x4 acc0 = {0.f, 0.f, 0.f, 0.f};
    f32x4 acc1 = {0.f, 0.f, 0.f, 0.f};

    // stage W chunk cc (16 rows x 256B) into wbuf[wv_][s]: 4 GLD16,
    // row swizzle applied on the per-lane global source (byte ^ ((row&7)<<4))
    #define WSTAGE(s, cc)                                                       \
    do {                                                                        \
        _Pragma("unroll")                                                       \
        for (int j_ = 0; j_ < 4; ++j_) {                                        \
            const int row_ = 4 * j_ + (lane >> 4);                              \
            const char* src_ = (const char*)(W                                  \
                + (size_t)(o_base + row_) * K_TOTAL + (size_t)(cc) * 64)        \
                + ((((lane & 15) << 4)) ^ ((row_ & 7) << 4));                   \
            GLD16(src_, (char*)&wbuf[wv_][s][4 * j_][0]);                       \
        }                                                                       \
    } while (0)

    // compute f chunk cc (64k x 32b bf16) into fbuf[wv_][s]: 4 units/lane
    #define FCOMP(s, cc)                                                        \
    do {                                                                        \
        _Pragma("unroll")                                                       \
        for (int i_ = 0; i_ < 4; ++i_) {                                        \
            const int u_  = lane + i_ * 64;      /* unit = koctet*32 + b */     \
            const int kb_ = u_ >> 5;             /* 0..7 */                     \
            const int b_  = u_ & 31;                                            \
            const int k0_ = (cc) * 64 + kb_ * 8;                                \
            float v_[8];                                                        \
            if (k0_ < IN_DIM) {                                                 \
                _Pragma("unroll")                                               \
                for (int e_ = 0; e_ < 8; ++e_)                                  \
                    v_[e_] = xT[(k0_ + e_) * B_SZ + b_];                        \
            } else {                                                            \
                int t_ = k0_ - IN_DIM;                                          \
                float disc_ = 4198401.0f - 8.0f * (float)t_;                    \
                int r_ = (int)((2049.0f - sqrtf(disc_)) * 0.5f);                \
                int off_ = r_ * IN_DIM - ((r_ * (r_ - 1)) >> 1);                \
                if (t_ < off_) { --r_; off_ = r_ * IN_DIM - ((r_ * (r_ - 1)) >> 1); } \
                else if (t_ >= off_ + (IN_DIM - r_)) { off_ += IN_DIM - r_; ++r_; }   \
                int c2_ = r_ + (t_ - off_);                                     \
                _Pragma("unroll")                                               \
                for (int e_ = 0; e_ < 8; ++e_) {                                \
                    v_[e_] = xT[r_ * B_SZ + b_] * xT[c2_ * B_SZ + b_];          \
                    if (c2_ == IN_DIM - 1) { ++r_; c2_ = r_; } else { ++c2_; }  \
                }                                                               \
            }                                                                   \
            int4 pk_;                                                           \
            pk_.x = (int)pk2(v_[0], v_[1]);                                     \
            pk_.y = (int)pk2(v_[2], v_[3]);                                     \
            pk_.z = (int)pk2(v_[4], v_[5]);                                     \
            pk_.w = (int)pk2(v_[6], v_[7]);                                     \
            fbuf[wv_][s][u_] = pk_;                                             \
        }                                                                       \
    } while (0)

    // 64-k chunk: 2 k-steps of 32; per q: W slots q*8+lkb*2 (^row swz), 2 MFMA
    #define COMPUTE(s)                                                          \
    do {                                                                        \
        const int s7_ = lrow & 7;                                               \
        _Pragma("unroll")                                                       \
        for (int q_ = 0; q_ < 2; ++q_) {                                        \
            const int sl_ = q_ * 8 + lkb * 2;                                   \
            const float4 f0_ = __builtin_bit_cast(float4, wbuf[wv_][s][lrow][sl_ ^ s7_]);       \
            const float4 f1_ = __builtin_bit_cast(float4, wbuf[wv_][s][lrow][(sl_ + 1) ^ s7_]); \
            int4 tw_;                                                           \
            tw_.x = (int)pk2(f0_.x, f0_.y);                                     \
            tw_.y = (int)pk2(f0_.z, f0_.w);                                     \
            tw_.z = (int)pk2(f1_.x, f1_.y);                                     \
            tw_.w = (int)pk2(f1_.z, f1_.w);                                     \
            const bfrag bw_ = __builtin_bit_cast(bfrag, tw_);                   \
            const int ub_ = (q_ * 4 + lkb) * 32 + lrow;                         \
            const bfrag a0_ = __builtin_bit_cast(bfrag, fbuf[wv_][s][ub_]);     \
            const bfrag a1_ = __builtin_bit_cast(bfrag, fbuf[wv_][s][ub_ + 16]);\
            acc0 = __builtin_amdgcn_mfma_f32_16x16x32_bf16(a0_, bw_, acc0, 0, 0, 0); \
            acc1 = __builtin_amdgcn_mfma_f32_16x16x32_bf16(a1_, bw_, acc1, 0, 0, 0); \
        }                                                                       \
    } while (0)

    // chunks owned: c = kseg + t*64 < 8216  ->  n = 129 (kseg<24) else 128
    const int n = (kseg < 24) ? 129 : 128;
    int c = kseg;

    // prologue: f first (its xT loads drain inside), W GLD16s issued last
    FCOMP(0, c);
    FCOMP(1, c + KSEG);
    __builtin_amdgcn_sched_barrier(0);
    WSTAGE(0, c);                                // 4 DMA
    WSTAGE(1, c + KSEG);                         // 8 in flight

    for (int t = 0; t < n; ++t) {
        if (t < n - 1)
            asm volatile("s_waitcnt vmcnt(4)" ::: "memory");   // W(t) landed
        else
            asm volatile("s_waitcnt vmcnt(0)" ::: "memory");
        COMPUTE(t & 1);
        if (t + 2 < n) {
            FCOMP(t & 1, c + 2 * KSEG);          // xT loads retire inside
            __builtin_amdgcn_sched_barrier(0);   // keep GLD16 issue AFTER them
            WSTAGE(t & 1, c + 2 * KSEG);         // prefetch rides 2 periods
        }
        c += KSEG;
    }

    #undef COMPUTE
    #undef FCOMP
    #undef WSTAGE

    // C layout: C[b=(lane>>4)*4+reg][o=lane&15]; plain stores, no atomics
    float* pb = partial + (size_t)kseg * (B_SZ * OUT_DIM) + o_base + lrow;
    const int r0 = lkb * 4;
    #pragma unroll
    for (int r = 0; r < 4; ++r) {
        pb[(size_t)(r0 + r) * OUT_DIM]      = acc0[r];
        pb[(size_t)(16 + r0 + r) * OUT_DIM] = acc1[r];
    }
}

// ------------- kernel C: reduce 64 partials + bias -> out
__global__ __launch_bounds__(256)
void reduce_kernel(const float* __restrict__ partial,
                   const float* __restrict__ bias,
                   float* __restrict__ out)
{
    const int idx = blockIdx.x * 256 + threadIdx.x;   // 0..16383
    float s = bias[idx & (OUT_DIM - 1)];
    const float* p = partial + idx;
    #pragma unroll 8
    for (int kg = 0; kg < KSEG; ++kg)
        s += p[(size_t)kg * (B_SZ * OUT_DIM)];
    out[idx] = s;
}

// ------------------------------------------------- fallback (proven v2 path)
__global__ __launch_bounds__(512, 2)
void qgemm_fallback_kernel(const float* __restrict__ x,
                           const float* __restrict__ W,
                           float* __restrict__ out)
{
    __shared__ float xt[B_SZ][512];

    const int tid  = threadIdx.x;
    const int lane = tid & 63;
    const int wave = tid >> 6;
    const int bgrp = wave & 3;
    const int ogrp = wave >> 2;

    const int og  = blockIdx.x & 31;
    const int kgf = blockIdx.x >> 5;

    const int o_base = og * 16 + ogrp * 8;
    const int b_base = bgrp * 8;

    float acc[8][8];
    #pragma unroll
    for (int i = 0; i < 8; ++i)
        #pragma unroll
        for (int o = 0; o < 8; ++o) acc[i][o] = 0.f;

    const int nch = (K_TOTAL + 511) / 512;
    for (int chunk = kgf; chunk < nch; chunk += 16) {
        const int k = chunk * 512 + tid;
        __syncthreads();
        if (k < IN_DIM) {
            #pragma unroll
            for (int b = 0; b < B_SZ; ++b)
                xt[b][tid] = x[b * IN_DIM + k];
        } else {
            const int t = k - IN_DIM;
            double disc = 4198401.0 - 8.0 * (double)t;
            int r = (int)((2049.0 - sqrt(disc)) * 0.5);
            int off = r * IN_DIM - ((r * (r - 1)) >> 1);
            if (t < off) { --r; off = r * IN_DIM - ((r * (r - 1)) >> 1); }
            else if (t >= off + (IN_DIM - r)) { off += IN_DIM - r; ++r; }
            const int ccol = r + (t - off);
            #pragma unroll
            for (int b = 0; b < B_SZ; ++b)
                xt[b][tid] = x[b * IN_DIM + r] * x[b * IN_DIM + ccol];
        }
        __syncthreads();

        const float* wrow = W + (size_t)o_base * K_TOTAL + (size_t)chunk * 512;
        #pragma unroll
        for (int pass = 0; pass < 2; ++pass) {
            const int kk = pass * 256 + lane * 4;
            float4 wv[8];
            #pragma unroll
            for (int o = 0; o < 8; ++o)
                wv[o] = *(const float4*)(wrow + (size_t)o * K_TOTAL + kk);
            float4 xv[8];
            #pragma unroll
            for (int i = 0; i < 8; ++i)
                xv[i] = *(const float4*)&xt[b_base + i][kk];
            #pragma unroll
            for (int o = 0; o < 8; ++o)
                #pragma unroll
                for (int i = 0; i < 8; ++i)
                    acc[i][o] += xv[i].x * wv[o].x + xv[i].y * wv[o].y
                               + xv[i].z * wv[o].z + xv[i].w * wv[o].w;
        }
    }

    #pragma unroll
    for (int i = 0; i < 8; ++i)
        #pragma unroll
        for (int o = 0; o < 8; ++o) {
            float v = acc[i][o];
            #pragma unroll
            for (int m = 1; m < 64; m <<= 1)
                v += __shfl_xor(v, m);
            acc[i][o] = v;
        }

    if (lane == 0) {
        #pragma unroll
        for (int i = 0; i < 8; ++i)
            #pragma unroll
            for (int o = 0; o < 8; ++o)
                atomicAdd(&out[(b_base + i) * OUT_DIM + o_base + o], acc[i][o]);
    }
}

extern "C" void kernel_launch(void* const* d_in, const int* in_sizes, int n_in,
                              void* d_out, int out_size, void* d_ws, size_t ws_size,
                              hipStream_t stream)
{
    const float* x    = (const float*)d_in[0];   // [32,1024] fp32
    const float* W    = (const float*)d_in[1];   // [512, 525824] fp32
    const float* bias = (const float*)d_in[2];   // [512] fp32
    float* out = (float*)d_out;                  // [32,512] fp32

    if (ws_size >= NEED_WS) {
        float* part = (float*)d_ws;
        float* xT   = (float*)((char*)d_ws + P_BYTES);
        hipLaunchKernelGGL(xpose_kernel, dim3(128), dim3(256), 0, stream, x, xT);
        hipLaunchKernelGGL(qgemm_mfma_kernel, dim3(512), dim3(256), 0, stream,
                           xT, W, part);
        hipLaunchKernelGGL(reduce_kernel, dim3(64), dim3(256), 0, stream,
                           part, bias, out);
    } else {
        hipLaunchKernelGGL(bias_init_kernel, dim3(64), dim3(256), 0, stream, bias, out);
        hipLaunchKernelGGL(qgemm_fallback_kernel, dim3(512), dim3(512), 0, stream,
                           x, W, out);
    }
}

// Round 22
// 344.222 us; speedup vs baseline: 1.5707x; 1.5707x over previous
//
#include <hip/hip_runtime.h>
#include <hip/hip_bf16.h>

#define B_SZ     32
#define IN_DIM   1024
#define K_TOTAL  525824          // 1024 linear + 524800 triu = 4108 * 128
#define OUT_DIM  512
#define NCH      4108            // 128-k chunks
#define KGN      128             // k-segment groups (chunk stride)
#define P_BYTES  ((size_t)KGN * B_SZ * OUT_DIM * 4)   // 8.4 MB partials
#define XT_BYTES ((size_t)IN_DIM * B_SZ * 4)          // 128 KB transposed x
#define NEED_WS  (P_BYTES + XT_BYTES)

typedef __attribute__((ext_vector_type(8))) short bfrag;   // 8 bf16 = 4 VGPR
typedef __attribute__((ext_vector_type(4))) float f32x4;

// async global->LDS, 16B per lane; LDS dest = wave-uniform base + lane*16,
// global source address is PER-LANE (swizzle goes on the source).
#define GLD16(g, l) __builtin_amdgcn_global_load_lds(                      \
    (const __attribute__((address_space(1))) void*)(g),                    \
    (__attribute__((address_space(3))) void*)(l), 16, 0, 0)

// fp32 -> bf16 round-to-nearest-even (pure integer)
__device__ inline unsigned bf16r(float f)
{
    unsigned u = __builtin_bit_cast(unsigned, f);
    return (u + 0x7FFFu + ((u >> 16) & 1u)) >> 16;
}
__device__ inline unsigned pk2(float a, float b)
{
    return bf16r(a) | (bf16r(b) << 16);
}

// ---------------------------------------------------------------- bias init (fallback path only)
__global__ void bias_init_kernel(const float* __restrict__ bias, float* __restrict__ out)
{
    int i = blockIdx.x * 256 + threadIdx.x;     // 16384 total
    out[i] = bias[i & (OUT_DIM - 1)];
}

// ------------- kernel A: transpose x -> xT[k][b] (128 KB, L2-resident)
__global__ __launch_bounds__(256)
void xpose_kernel(const float* __restrict__ x, float* __restrict__ xT)
{
    const int idx = blockIdx.x * 256 + threadIdx.x;   // 0..32767
    const int k = idx >> 5, b = idx & 31;
    xT[idx] = x[b * IN_DIM + k];                      // write coalesced
}

// ------------- kernel B: fused MFMA GEMM, 3-buffer / ONE-barrier pipeline.
// Per period t: wait vmcnt(8) (W(t) landed; W(t+1) in flight) + lgkmcnt(0)
// -> s_barrier (all waves past COMPUTE(t-1)) -> COMPUTE(t) -> FCOMP(t+2)
// -> WSTAGE(t+2) into buffer (t+2)%3 == (t-1)%3 (its readers are done).
// No second rendezvous: staging issues immediately after compute.
__global__ __launch_bounds__(256, 1)
void qgemm_mfma_kernel(const float* __restrict__ xT,
                       const float* __restrict__ W,
                       float* __restrict__ partial)
{
    __shared__ int4 wlds[3][64][32];             // 96 KB (swizzled rows)
    __shared__ int4 fbuf[3][512];                // 24 KB  (120 KB total, 1 blk/CU)

    const int tid  = threadIdx.x;
    const int lane = tid & 63;
    const int wv_  = tid >> 6;                   // 0..3
    const int lrow = lane & 15;                  // A row / B col within tile
    const int lkb  = lane >> 4;                  // k-octet group 0..3

    const int og = blockIdx.x >> 7;              // 0..7
    const int kg = blockIdx.x & (KGN - 1);       // 0..127

    const int o_blk  = og * 64;
    const int o_base = o_blk + wv_ * 16;

    f32x4 acc0 = {0.f, 0.f, 0.f, 0.f};
    f32x4 acc1 = {0.f, 0.f, 0.f, 0.f};

    #define WSTAGE(s, cc)                                                       \
    do {                                                                        \
        _Pragma("unroll")                                                       \
        for (int j_ = 0; j_ < 8; ++j_) {                                        \
            const int rl_ = 2 * j_ + (lane >> 5);                               \
            const char* src_ = (const char*)(W                                  \
                + (size_t)(o_blk + wv_ * 16 + rl_) * K_TOTAL                    \
                + (size_t)(cc) * 128)                                           \
                + (((lane & 31) << 4) ^ ((rl_ & 7) << 4));                      \
            GLD16(src_, (char*)&wlds[s][wv_ * 16 + 2 * j_][0]);                 \
        }                                                                       \
    } while (0)

    #define FCOMP(s, cc)                                                        \
    do {                                                                        \
        _Pragma("unroll")                                                       \
        for (int i_ = 0; i_ < 2; ++i_) {                                        \
            const int u_  = tid + i_ * 256;      /* unit = koctet*32 + b */     \
            const int kb_ = u_ >> 5;                                            \
            const int b_  = u_ & 31;                                            \
            const int k0_ = (cc) * 128 + kb_ * 8;                               \
            float v_[8];                                                        \
            if (k0_ < IN_DIM) {                                                 \
                _Pragma("unroll")                                               \
                for (int e_ = 0; e_ < 8; ++e_)                                  \
                    v_[e_] = xT[(k0_ + e_) * B_SZ + b_];                        \
            } else {                                                            \
                int t_ = k0_ - IN_DIM;                                          \
                float disc_ = 4198401.0f - 8.0f * (float)t_;                    \
                int r_ = (int)((2049.0f - sqrtf(disc_)) * 0.5f);                \
                int off_ = r_ * IN_DIM - ((r_ * (r_ - 1)) >> 1);                \
                if (t_ < off_) { --r_; off_ = r_ * IN_DIM - ((r_ * (r_ - 1)) >> 1); } \
                else if (t_ >= off_ + (IN_DIM - r_)) { off_ += IN_DIM - r_; ++r_; }   \
                int c2_ = r_ + (t_ - off_);                                     \
                _Pragma("unroll")                                               \
                for (int e_ = 0; e_ < 8; ++e_) {                                \
                    v_[e_] = xT[r_ * B_SZ + b_] * xT[c2_ * B_SZ + b_];          \
                    if (c2_ == IN_DIM - 1) { ++r_; c2_ = r_; } else { ++c2_; }  \
                }                                                               \
            }                                                                   \
            int4 pk_;                                                           \
            pk_.x = (int)pk2(v_[0], v_[1]);                                     \
            pk_.y = (int)pk2(v_[2], v_[3]);                                     \
            pk_.z = (int)pk2(v_[4], v_[5]);                                     \
            pk_.w = (int)pk2(v_[6], v_[7]);                                     \
            fbuf[s][u_] = pk_;                                                  \
        }                                                                       \
    } while (0)

    #define COMPUTE(s)                                                          \
    do {                                                                        \
        const int r_  = wv_ * 16 + lrow;                                        \
        const int s7_ = lrow & 7;                                               \
        _Pragma("unroll")                                                       \
        for (int q_ = 0; q_ < 4; ++q_) {                                        \
            const int sl_ = lkb * 2 + q_ * 8;                                   \
            const float4 f0_ = __builtin_bit_cast(float4, wlds[s][r_][sl_ ^ s7_]);       \
            const float4 f1_ = __builtin_bit_cast(float4, wlds[s][r_][(sl_ + 1) ^ s7_]); \
            int4 tw_;                                                           \
            tw_.x = (int)pk2(f0_.x, f0_.y);                                     \
            tw_.y = (int)pk2(f0_.z, f0_.w);                                     \
            tw_.z = (int)pk2(f1_.x, f1_.y);                                     \
            tw_.w = (int)pk2(f1_.z, f1_.w);                                     \
            const bfrag bw_ = __builtin_bit_cast(bfrag, tw_);                   \
            const int ub_ = (q_ * 4 + lkb) * 32 + lrow;                         \
            const bfrag a0_ = __builtin_bit_cast(bfrag, fbuf[s][ub_]);          \
            const bfrag a1_ = __builtin_bit_cast(bfrag, fbuf[s][ub_ + 16]);     \
            acc0 = __builtin_amdgcn_mfma_f32_16x16x32_bf16(a0_, bw_, acc0, 0, 0, 0); \
            acc1 = __builtin_amdgcn_mfma_f32_16x16x32_bf16(a1_, bw_, acc1, 0, 0, 0); \
        }                                                                       \
    } while (0)

    const int n = (kg < 12) ? 33 : 32;           // chunks owned: kg + t*128 < 4108
    int c = kg;

    // prologue: f first (xT loads drain inside), W GLD16s issued last
    FCOMP(0, c);
    FCOMP(1, c + KGN);
    __builtin_amdgcn_sched_barrier(0);
    WSTAGE(0, c);                                // 8 DMA
    WSTAGE(1, c + KGN);                          // 16 in flight

    int sC = 0;                                  // buffer to compute  (t%3)
    int sS = 2;                                  // buffer to stage    ((t+2)%3)
    for (int t = 0; t < n; ++t) {
        if (t < n - 1)
            asm volatile("s_waitcnt vmcnt(8) lgkmcnt(0)" ::: "memory");  // W(t) landed
        else
            asm volatile("s_waitcnt vmcnt(0) lgkmcnt(0)" ::: "memory");
        __builtin_amdgcn_s_barrier();            // all waves past COMPUTE(t-1)
        COMPUTE(sC);
        if (t + 2 < n) {
            FCOMP(sS, c + 2 * KGN);              // xT loads retire inside
            __builtin_amdgcn_sched_barrier(0);   // keep GLD16 issue AFTER them
            WSTAGE(sS, c + 2 * KGN);             // no rendezvous behind this
        }
        sC = (sC == 2) ? 0 : sC + 1;
        sS = (sS == 2) ? 0 : sS + 1;
        c += KGN;
    }

    #undef COMPUTE
    #undef FCOMP
    #undef WSTAGE

    // C layout: C[b = (lane>>4)*4 + reg][o = lane&15]; plain stores to partial[kg]
    float* pb = partial + (size_t)kg * (B_SZ * OUT_DIM) + o_base + lrow;
    const int r0 = lkb * 4;
    #pragma unroll
    for (int r = 0; r < 4; ++r) {
        pb[(size_t)(r0 + r) * OUT_DIM]      = acc0[r];
        pb[(size_t)(16 + r0 + r) * OUT_DIM] = acc1[r];
    }
}

// ------------- kernel C: reduce 128 partials + bias -> out
__global__ __launch_bounds__(256)
void reduce_kernel(const float* __restrict__ partial,
                   const float* __restrict__ bias,
                   float* __restrict__ out)
{
    const int idx = blockIdx.x * 256 + threadIdx.x;   // 0..16383
    float s = bias[idx & (OUT_DIM - 1)];
    const float* p = partial + idx;
    #pragma unroll 8
    for (int kg = 0; kg < KGN; ++kg)
        s += p[(size_t)kg * (B_SZ * OUT_DIM)];
    out[idx] = s;
}

// ------------------------------------------------- fallback (proven v2 path)
__global__ __launch_bounds__(512, 2)
void qgemm_fallback_kernel(const float* __restrict__ x,
                           const float* __restrict__ W,
                           float* __restrict__ out)
{
    __shared__ float xt[B_SZ][512];

    const int tid  = threadIdx.x;
    const int lane = tid & 63;
    const int wave = tid >> 6;
    const int bgrp = wave & 3;
    const int ogrp = wave >> 2;

    const int og  = blockIdx.x & 31;
    const int kgf = blockIdx.x >> 5;

    const int o_base = og * 16 + ogrp * 8;
    const int b_base = bgrp * 8;

    float acc[8][8];
    #pragma unroll
    for (int i = 0; i < 8; ++i)
        #pragma unroll
        for (int o = 0; o < 8; ++o) acc[i][o] = 0.f;

    const int nch = (K_TOTAL + 511) / 512;
    for (int chunk = kgf; chunk < nch; chunk += 16) {
        const int k = chunk * 512 + tid;
        __syncthreads();
        if (k < IN_DIM) {
            #pragma unroll
            for (int b = 0; b < B_SZ; ++b)
                xt[b][tid] = x[b * IN_DIM + k];
        } else {
            const int t = k - IN_DIM;
            double disc = 4198401.0 - 8.0 * (double)t;
            int r = (int)((2049.0 - sqrt(disc)) * 0.5);
            int off = r * IN_DIM - ((r * (r - 1)) >> 1);
            if (t < off) { --r; off = r * IN_DIM - ((r * (r - 1)) >> 1); }
            else if (t >= off + (IN_DIM - r)) { off += IN_DIM - r; ++r; }
            const int ccol = r + (t - off);
            #pragma unroll
            for (int b = 0; b < B_SZ; ++b)
                xt[b][tid] = x[b * IN_DIM + r] * x[b * IN_DIM + ccol];
        }
        __syncthreads();

        const float* wrow = W + (size_t)o_base * K_TOTAL + (size_t)chunk * 512;
        #pragma unroll
        for (int pass = 0; pass < 2; ++pass) {
            const int kk = pass * 256 + lane * 4;
            float4 wv[8];
            #pragma unroll
            for (int o = 0; o < 8; ++o)
                wv[o] = *(const float4*)(wrow + (size_t)o * K_TOTAL + kk);
            float4 xv[8];
            #pragma unroll
            for (int i = 0; i < 8; ++i)
                xv[i] = *(const float4*)&xt[b_base + i][kk];
            #pragma unroll
            for (int o = 0; o < 8; ++o)
                #pragma unroll
                for (int i = 0; i < 8; ++i)
                    acc[i][o] += xv[i].x * wv[o].x + xv[i].y * wv[o].y
                               + xv[i].z * wv[o].z + xv[i].w * wv[o].w;
        }
    }

    #pragma unroll
    for (int i = 0; i < 8; ++i)
        #pragma unroll
        for (int o = 0; o < 8; ++o) {
            float v = acc[i][o];
            #pragma unroll
            for (int m = 1; m < 64; m <<= 1)
                v += __shfl_xor(v, m);
            acc[i][o] = v;
        }

    if (lane == 0) {
        #pragma unroll
        for (int i = 0; i < 8; ++i)
            #pragma unroll
            for (int o = 0; o < 8; ++o)
                atomicAdd(&out[(b_base + i) * OUT_DIM + o_base + o], acc[i][o]);
    }
}

extern "C" void kernel_launch(void* const* d_in, const int* in_sizes, int n_in,
                              void* d_out, int out_size, void* d_ws, size_t ws_size,
                              hipStream_t stream)
{
    const float* x    = (const float*)d_in[0];   // [32,1024] fp32
    const float* W    = (const float*)d_in[1];   // [512, 525824] fp32
    const float* bias = (const float*)d_in[2];   // [512] fp32
    float* out = (float*)d_out;                  // [32,512] fp32

    if (ws_size >= NEED_WS) {
        float* part = (float*)d_ws;
        float* xT   = (float*)((char*)d_ws + P_BYTES);
        hipLaunchKernelGGL(xpose_kernel, dim3(128), dim3(256), 0, stream, x, xT);
        hipLaunchKernelGGL(qgemm_mfma_kernel, dim3(8 * KGN), dim3(256), 0, stream,
                           xT, W, part);
        hipLaunchKernelGGL(reduce_kernel, dim3(64), dim3(256), 0, stream,
                           part, bias, out);
    } else {
        hipLaunchKernelGGL(bias_init_kernel, dim3(64), dim3(256), 0, stream, bias, out);
        hipLaunchKernelGGL(qgemm_fallback_kernel, dim3(512), dim3(512), 0, stream,
                           x, W, out);
    }
}

// Round 23
// 285.850 us; speedup vs baseline: 1.8915x; 1.2042x over previous
//
#include <hip/hip_runtime.h>
#include <hip/hip_bf16.h>

#define B_SZ     32
#define IN_DIM   1024
#define K_TOTAL  525824          // 1024 linear + 524800 triu = 4108 * 128
#define OUT_DIM  512
#define NCH      4108            // 128-k chunks
#define KSEG     32              // k-segments (chunk stride)
#define F_BYTES  ((size_t)NCH * 8192)                 // 33.65 MB packed bf16 features
#define P_BYTES  ((size_t)KSEG * B_SZ * OUT_DIM * 4)  // 2 MB partials
#define NEED_WS  (F_BYTES + P_BYTES)

typedef __attribute__((ext_vector_type(8))) short bfrag;   // 8 bf16 = 4 VGPR
typedef __attribute__((ext_vector_type(4))) float f32x4;

// async global->LDS, 16B per lane; LDS dest = wave-uniform base + lane*16,
// global source address is PER-LANE (swizzle goes on the source).
#define GLD16(g, l) __builtin_amdgcn_global_load_lds(                      \
    (const __attribute__((address_space(1))) void*)(g),                    \
    (__attribute__((address_space(3))) void*)(l), 16, 0, 0)

// fp32 -> bf16 round-to-nearest-even (pure integer)
__device__ inline unsigned bf16r(float f)
{
    unsigned u = __builtin_bit_cast(unsigned, f);
    return (u + 0x7FFFu + ((u >> 16) & 1u)) >> 16;
}
__device__ inline unsigned pk2(float a, float b)
{
    return bf16r(a) | (bf16r(b) << 16);
}

// ---------------------------------------------------------------- bias init (fallback path only)
__global__ void bias_init_kernel(const float* __restrict__ bias, float* __restrict__ out)
{
    int i = blockIdx.x * 256 + threadIdx.x;     // 16384 total
    out[i] = bias[i & (OUT_DIM - 1)];
}

// ------------- kernel A: feature expand -> bf16, MFMA-A-fragment packed
// layout: unit u = (chunk*16 + koctet)*32 + b holds f[b][chunk*128+koctet*8 .. +7]
__global__ __launch_bounds__(256)
void feat_pack_kernel(const float* __restrict__ x, int4* __restrict__ fp)
{
    const int chunk = blockIdx.x;               // 0..4107
    const int tid   = threadIdx.x;

    #pragma unroll
    for (int i = 0; i < 2; ++i) {
        const int unit = tid + i * 256;         // 0..511
        const int kb   = unit >> 5;             // k-octet 0..15
        const int b    = unit & 31;
        const int k0   = chunk * 128 + kb * 8;
        const float* xb = x + b * IN_DIM;

        float v[8];
        if (chunk < 8) {                        // linear features (k < 1024)
            #pragma unroll
            for (int e = 0; e < 8; ++e) v[e] = xb[k0 + e];
        } else {                                // quadratic: walk (r,c) from one sqrt
            int t = k0 - IN_DIM;
            float disc = 4198401.0f - 8.0f * (float)t;   // 2049^2 - 8t, exact in fp32
            int r = (int)((2049.0f - sqrtf(disc)) * 0.5f);
            int off = r * IN_DIM - ((r * (r - 1)) >> 1);
            if (t < off) { --r; off = r * IN_DIM - ((r * (r - 1)) >> 1); }
            else if (t >= off + (IN_DIM - r)) { off += IN_DIM - r; ++r; }
            int c_ = r + (t - off);
            #pragma unroll
            for (int e = 0; e < 8; ++e) {
                v[e] = xb[r] * xb[c_];
                if (c_ == IN_DIM - 1) { ++r; c_ = r; } else { ++c_; }
            }
        }
        int4 pk;
        pk.x = (int)pk2(v[0], v[1]);
        pk.y = (int)pk2(v[2], v[3]);
        pk.z = (int)pk2(v[4], v[5]);
        pk.w = (int)pk2(v[6], v[7]);
        fp[(size_t)chunk * 512 + unit] = pk;
    }
}

// ------------- kernel B: WAVE-AUTONOMOUS MFMA GEMM (probe-exact DMA shape).
// Each wave: private 16 o-rows x one k-segment; private LDS (W 2x8KB swz +
// f 2x8KB); per period 16 GLD16 (8 W @ 2rows x 512B + 8 f linear), counted
// vmcnt(16), ZERO barriers, ZERO lgkm waits. 256 blocks = 1/CU, 4 waves.
__global__ __launch_bounds__(256, 1)
void qgemm_mfma_kernel(const int4* __restrict__ fp,
                       const float* __restrict__ W,
                       float* __restrict__ partial)
{
    __shared__ int4 wlds[4][2][16][32];          // 64 KB: per-wave W, swizzled rows
    __shared__ int4 flds[4][2][512];             // 64 KB: per-wave f fragments

    const int tid  = threadIdx.x;
    const int lane = tid & 63;
    const int wv_  = tid >> 6;                   // 0..3
    const int lrow = lane & 15;                  // A row / B col within tile
    const int lkb  = lane >> 4;                  // k-octet group 0..3

    const int kseg = blockIdx.x & 31;            // same-kseg blocks stride 32 -> co-XCD
    const int opos = (blockIdx.x >> 5) * 4 + wv_;// 0..31
    const int o_base = opos * 16;

    f32x4 acc0 = {0.f, 0.f, 0.f, 0.f};
    f32x4 acc1 = {0.f, 0.f, 0.f, 0.f};

    // stage W chunk cc into wlds[wv_][s]: 8 GLD16, 2 rows x 512B each,
    // per-lane source pre-swizzled (byte ^ ((row&7)<<4)), linear LDS dest
    #define WSTAGE(s, cc)                                                       \
    do {                                                                        \
        _Pragma("unroll")                                                       \
        for (int j_ = 0; j_ < 8; ++j_) {                                        \
            const int rl_ = 2 * j_ + (lane >> 5);                               \
            const char* src_ = (const char*)(W                                  \
                + (size_t)(o_base + rl_) * K_TOTAL + (size_t)(cc) * 128)        \
                + (((lane & 31) << 4) ^ ((rl_ & 7) << 4));                      \
            GLD16(src_, (char*)&wlds[wv_][s][2 * j_][0]);                       \
        }                                                                       \
    } while (0)

    // stage f chunk cc (8 KB linear) into flds[wv_][s]: 8 GLD16
    #define FSTAGE(s, cc)                                                       \
    do {                                                                        \
        const char* gp_ = (const char*)fp + (size_t)(cc) * 8192                 \
                        + (size_t)(lane << 4);                                  \
        _Pragma("unroll")                                                       \
        for (int j_ = 0; j_ < 8; ++j_)                                          \
            GLD16(gp_ + j_ * 1024, (char*)&flds[wv_][s][0] + j_ * 1024);        \
    } while (0)

    #define COMPUTE(s)                                                          \
    do {                                                                        \
        const int s7_ = lrow & 7;                                               \
        _Pragma("unroll")                                                       \
        for (int q_ = 0; q_ < 4; ++q_) {                                        \
            const int sl_ = lkb * 2 + q_ * 8;                                   \
            const float4 f0_ = __builtin_bit_cast(float4, wlds[wv_][s][lrow][sl_ ^ s7_]);       \
            const float4 f1_ = __builtin_bit_cast(float4, wlds[wv_][s][lrow][(sl_ + 1) ^ s7_]); \
            int4 tw_;                                                           \
            tw_.x = (int)pk2(f0_.x, f0_.y);                                     \
            tw_.y = (int)pk2(f0_.z, f0_.w);                                     \
            tw_.z = (int)pk2(f1_.x, f1_.y);                                     \
            tw_.w = (int)pk2(f1_.z, f1_.w);                                     \
            const bfrag bw_ = __builtin_bit_cast(bfrag, tw_);                   \
            const int ub_ = (q_ * 4 + lkb) * 32 + lrow;                         \
            const bfrag a0_ = __builtin_bit_cast(bfrag, flds[wv_][s][ub_]);     \
            const bfrag a1_ = __builtin_bit_cast(bfrag, flds[wv_][s][ub_ + 16]);\
            acc0 = __builtin_amdgcn_mfma_f32_16x16x32_bf16(a0_, bw_, acc0, 0, 0, 0); \
            acc1 = __builtin_amdgcn_mfma_f32_16x16x32_bf16(a1_, bw_, acc1, 0, 0, 0); \
        }                                                                       \
    } while (0)

    // chunks owned: c = kseg + t*32 < 4108 = 32*128 + 12
    const int n = (kseg < 12) ? 129 : 128;
    int c = kseg;

    FSTAGE(0, c);        WSTAGE(0, c);           // 16 DMA
    FSTAGE(1, c + KSEG); WSTAGE(1, c + KSEG);    // 32 in flight

    for (int t = 0; t < n; ++t) {
        if (t < n - 1)
            asm volatile("s_waitcnt vmcnt(16)" ::: "memory");  // stage(t) landed
        else
            asm volatile("s_waitcnt vmcnt(0)" ::: "memory");
        COMPUTE(t & 1);
        if (t + 2 < n) {
            FSTAGE(t & 1, c + 2 * KSEG);         // refill just-consumed buffers
            WSTAGE(t & 1, c + 2 * KSEG);
        }
        c += KSEG;
    }

    #undef COMPUTE
    #undef FSTAGE
    #undef WSTAGE

    // C layout: C[b = (lane>>4)*4 + reg][o = lane&15]; plain stores to partial[kseg]
    float* pb = partial + (size_t)kseg * (B_SZ * OUT_DIM) + o_base + lrow;
    const int r0 = lkb * 4;
    #pragma unroll
    for (int r = 0; r < 4; ++r) {
        pb[(size_t)(r0 + r) * OUT_DIM]      = acc0[r];
        pb[(size_t)(16 + r0 + r) * OUT_DIM] = acc1[r];
    }
}

// ------------- kernel C: reduce 32 partials + bias -> out
__global__ __launch_bounds__(256)
void reduce_kernel(const float* __restrict__ partial,
                   const float* __restrict__ bias,
                   float* __restrict__ out)
{
    const int idx = blockIdx.x * 256 + threadIdx.x;   // 0..16383
    float s = bias[idx & (OUT_DIM - 1)];
    const float* p = partial + idx;
    #pragma unroll 8
    for (int kg = 0; kg < KSEG; ++kg)
        s += p[(size_t)kg * (B_SZ * OUT_DIM)];
    out[idx] = s;
}

// ------------------------------------------------- fallback (proven v2 path)
__global__ __launch_bounds__(512, 2)
void qgemm_fallback_kernel(const float* __restrict__ x,
                           const float* __restrict__ W,
                           float* __restrict__ out)
{
    __shared__ float xt[B_SZ][512];

    const int tid  = threadIdx.x;
    const int lane = tid & 63;
    const int wave = tid >> 6;
    const int bgrp = wave & 3;
    const int ogrp = wave >> 2;

    const int og  = blockIdx.x & 31;
    const int kgf = blockIdx.x >> 5;

    const int o_base = og * 16 + ogrp * 8;
    const int b_base = bgrp * 8;

    float acc[8][8];
    #pragma unroll
    for (int i = 0; i < 8; ++i)
        #pragma unroll
        for (int o = 0; o < 8; ++o) acc[i][o] = 0.f;

    const int nch = (K_TOTAL + 511) / 512;
    for (int chunk = kgf; chunk < nch; chunk += 16) {
        const int k = chunk * 512 + tid;
        __syncthreads();
        if (k < IN_DIM) {
            #pragma unroll
            for (int b = 0; b < B_SZ; ++b)
                xt[b][tid] = x[b * IN_DIM + k];
        } else {
            const int t = k - IN_DIM;
            double disc = 4198401.0 - 8.0 * (double)t;
            int r = (int)((2049.0 - sqrt(disc)) * 0.5);
            int off = r * IN_DIM - ((r * (r - 1)) >> 1);
            if (t < off) { --r; off = r * IN_DIM - ((r * (r - 1)) >> 1); }
            else if (t >= off + (IN_DIM - r)) { off += IN_DIM - r; ++r; }
            const int ccol = r + (t - off);
            #pragma unroll
            for (int b = 0; b < B_SZ; ++b)
                xt[b][tid] = x[b * IN_DIM + r] * x[b * IN_DIM + ccol];
        }
        __syncthreads();

        const float* wrow = W + (size_t)o_base * K_TOTAL + (size_t)chunk * 512;
        #pragma unroll
        for (int pass = 0; pass < 2; ++pass) {
            const int kk = pass * 256 + lane * 4;
            float4 wv[8];
            #pragma unroll
            for (int o = 0; o < 8; ++o)
                wv[o] = *(const float4*)(wrow + (size_t)o * K_TOTAL + kk);
            float4 xv[8];
            #pragma unroll
            for (int i = 0; i < 8; ++i)
                xv[i] = *(const float4*)&xt[b_base + i][kk];
            #pragma unroll
            for (int o = 0; o < 8; ++o)
                #pragma unroll
                for (int i = 0; i < 8; ++i)
                    acc[i][o] += xv[i].x * wv[o].x + xv[i].y * wv[o].y
                               + xv[i].z * wv[o].z + xv[i].w * wv[o].w;
        }
    }

    #pragma unroll
    for (int i = 0; i < 8; ++i)
        #pragma unroll
        for (int o = 0; o < 8; ++o) {
            float v = acc[i][o];
            #pragma unroll
            for (int m = 1; m < 64; m <<= 1)
                v += __shfl_xor(v, m);
            acc[i][o] = v;
        }

    if (lane == 0) {
        #pragma unroll
        for (int i = 0; i < 8; ++i)
            #pragma unroll
            for (int o = 0; o < 8; ++o)
                atomicAdd(&out[(b_base + i) * OUT_DIM + o_base + o], acc[i][o]);
    }
}

extern "C" void kernel_launch(void* const* d_in, const int* in_sizes, int n_in,
                              void* d_out, int out_size, void* d_ws, size_t ws_size,
                              hipStream_t stream)
{
    const float* x    = (const float*)d_in[0];   // [32,1024] fp32
    const float* W    = (const float*)d_in[1];   // [512, 525824] fp32
    const float* bias = (const float*)d_in[2];   // [512] fp32
    float* out = (float*)d_out;                  // [32,512] fp32

    if (ws_size >= NEED_WS) {
        int4*  fpk  = (int4*)d_ws;
        float* part = (float*)((char*)d_ws + F_BYTES);
        hipLaunchKernelGGL(feat_pack_kernel, dim3(NCH), dim3(256), 0, stream, x, fpk);
        hipLaunchKernelGGL(qgemm_mfma_kernel, dim3(256), dim3(256), 0, stream,
                           fpk, W, part);
        hipLaunchKernelGGL(reduce_kernel, dim3(64), dim3(256), 0, stream,
                           part, bias, out);
    } else {
        hipLaunchKernelGGL(bias_init_kernel, dim3(64), dim3(256), 0, stream, bias, out);
        hipLaunchKernelGGL(qgemm_fallback_kernel, dim3(512), dim3(512), 0, stream,
                           x, W, out);
    }
}

// Round 24
// 256.915 us; speedup vs baseline: 2.1045x; 1.1126x over previous
//
#include <hip/hip_runtime.h>
#include <hip/hip_bf16.h>

#define B_SZ     32
#define IN_DIM   1024
#define K_TOTAL  525824          // 1024 linear + 524800 triu = 4108 * 128
#define OUT_DIM  512
#define NCH      4108            // 128-k chunks
#define KGN      128             // k-segment groups (chunk stride)
#define P_BYTES  ((size_t)KGN * B_SZ * OUT_DIM * 4)   // 8.4 MB partials
#define XT_BYTES ((size_t)IN_DIM * B_SZ * 4)          // 128 KB transposed x
#define NEED_WS  (P_BYTES + XT_BYTES)

typedef __attribute__((ext_vector_type(8))) short bfrag;   // 8 bf16 = 4 VGPR
typedef __attribute__((ext_vector_type(4))) float f32x4;

// async global->LDS, 16B per lane; LDS dest = wave-uniform base + lane*16,
// global source address is PER-LANE (swizzle goes on the source).
#define GLD16(g, l) __builtin_amdgcn_global_load_lds(                      \
    (const __attribute__((address_space(1))) void*)(g),                    \
    (__attribute__((address_space(3))) void*)(l), 16, 0, 0)

// fp32 -> bf16 round-to-nearest-even (pure integer)
__device__ inline unsigned bf16r(float f)
{
    unsigned u = __builtin_bit_cast(unsigned, f);
    return (u + 0x7FFFu + ((u >> 16) & 1u)) >> 16;
}
__device__ inline unsigned pk2(float a, float b)
{
    return bf16r(a) | (bf16r(b) << 16);
}

// ---------------------------------------------------------------- bias init (fallback path only)
__global__ void bias_init_kernel(const float* __restrict__ bias, float* __restrict__ out)
{
    int i = blockIdx.x * 256 + threadIdx.x;     // 16384 total
    out[i] = bias[i & (OUT_DIM - 1)];
}

// ------------- kernel A: transpose x -> xT[k][b] (128 KB, L2-resident)
__global__ __launch_bounds__(256)
void xpose_kernel(const float* __restrict__ x, float* __restrict__ xT)
{
    const int idx = blockIdx.x * 256 + threadIdx.x;   // 0..32767
    const int k = idx >> 5, b = idx & 31;
    xT[idx] = x[b * IN_DIM + k];                      // write coalesced
}

// ------------- kernel B: fused MFMA GEMM (best-known configuration, v18).
// W staged via global_load_lds (512B/row bursts, source-XOR-swizzled rows);
// f fragments computed on the fly from xT into LDS; split-K partial store.
__global__ __launch_bounds__(256, 2)
void qgemm_mfma_kernel(const float* __restrict__ xT,
                       const float* __restrict__ W,
                       float* __restrict__ partial)
{
    __shared__ int4 wlds[2][64][32];             // 64 KB (swizzled rows)
    __shared__ int4 fbuf[2][512];                // 16 KB

    const int tid  = threadIdx.x;
    const int lane = tid & 63;
    const int wv_  = tid >> 6;                   // 0..3
    const int lrow = lane & 15;                  // A row / B col within tile
    const int lkb  = lane >> 4;                  // k-octet group 0..3

    const int og = blockIdx.x >> 7;              // 0..7
    const int kg = blockIdx.x & (KGN - 1);       // 0..127 (bid%8 = kg%8 co-XCD)

    const int o_blk  = og * 64;
    const int o_base = o_blk + wv_ * 16;

    f32x4 acc0 = {0.f, 0.f, 0.f, 0.f};
    f32x4 acc1 = {0.f, 0.f, 0.f, 0.f};

    #define WSTAGE(s, cc)                                                       \
    do {                                                                        \
        _Pragma("unroll")                                                       \
        for (int j_ = 0; j_ < 8; ++j_) {                                        \
            const int rl_ = 2 * j_ + (lane >> 5);                               \
            const char* src_ = (const char*)(W                                  \
                + (size_t)(o_blk + wv_ * 16 + rl_) * K_TOTAL                    \
                + (size_t)(cc) * 128)                                           \
                + (((lane & 31) << 4) ^ ((rl_ & 7) << 4));                      \
            GLD16(src_, (char*)&wlds[s][wv_ * 16 + 2 * j_][0]);                 \
        }                                                                       \
    } while (0)

    #define FCOMP(s, cc)                                                        \
    do {                                                                        \
        _Pragma("unroll")                                                       \
        for (int i_ = 0; i_ < 2; ++i_) {                                        \
            const int u_  = tid + i_ * 256;      /* unit = koctet*32 + b */     \
            const int kb_ = u_ >> 5;                                            \
            const int b_  = u_ & 31;                                            \
            const int k0_ = (cc) * 128 + kb_ * 8;                               \
            float v_[8];                                                        \
            if (k0_ < IN_DIM) {                                                 \
                _Pragma("unroll")                                               \
                for (int e_ = 0; e_ < 8; ++e_)                                  \
                    v_[e_] = xT[(k0_ + e_) * B_SZ + b_];                        \
            } else {                                                            \
                int t_ = k0_ - IN_DIM;                                          \
                float disc_ = 4198401.0f - 8.0f * (float)t_;                    \
                int r_ = (int)((2049.0f - sqrtf(disc_)) * 0.5f);                \
                int off_ = r_ * IN_DIM - ((r_ * (r_ - 1)) >> 1);                \
                if (t_ < off_) { --r_; off_ = r_ * IN_DIM - ((r_ * (r_ - 1)) >> 1); } \
                else if (t_ >= off_ + (IN_DIM - r_)) { off_ += IN_DIM - r_; ++r_; }   \
                int c2_ = r_ + (t_ - off_);                                     \
                _Pragma("unroll")                                               \
                for (int e_ = 0; e_ < 8; ++e_) {                                \
                    v_[e_] = xT[r_ * B_SZ + b_] * xT[c2_ * B_SZ + b_];          \
                    if (c2_ == IN_DIM - 1) { ++r_; c2_ = r_; } else { ++c2_; }  \
                }                                                               \
            }                                                                   \
            int4 pk_;                                                           \
            pk_.x = (int)pk2(v_[0], v_[1]);                                     \
            pk_.y = (int)pk2(v_[2], v_[3]);                                     \
            pk_.z = (int)pk2(v_[4], v_[5]);                                     \
            pk_.w = (int)pk2(v_[6], v_[7]);                                     \
            fbuf[s][u_] = pk_;                                                  \
        }                                                                       \
    } while (0)

    #define COMPUTE(s)                                                          \
    do {                                                                        \
        const int r_  = wv_ * 16 + lrow;                                        \
        const int s7_ = lrow & 7;                                               \
        _Pragma("unroll")                                                       \
        for (int q_ = 0; q_ < 4; ++q_) {                                        \
            const int sl_ = lkb * 2 + q_ * 8;                                   \
            const float4 f0_ = __builtin_bit_cast(float4, wlds[s][r_][sl_ ^ s7_]);       \
            const float4 f1_ = __builtin_bit_cast(float4, wlds[s][r_][(sl_ + 1) ^ s7_]); \
            int4 tw_;                                                           \
            tw_.x = (int)pk2(f0_.x, f0_.y);                                     \
            tw_.y = (int)pk2(f0_.z, f0_.w);                                     \
            tw_.z = (int)pk2(f1_.x, f1_.y);                                     \
            tw_.w = (int)pk2(f1_.z, f1_.w);                                     \
            const bfrag bw_ = __builtin_bit_cast(bfrag, tw_);                   \
            const int ub_ = (q_ * 4 + lkb) * 32 + lrow;                         \
            const bfrag a0_ = __builtin_bit_cast(bfrag, fbuf[s][ub_]);          \
            const bfrag a1_ = __builtin_bit_cast(bfrag, fbuf[s][ub_ + 16]);     \
            acc0 = __builtin_amdgcn_mfma_f32_16x16x32_bf16(a0_, bw_, acc0, 0, 0, 0); \
            acc1 = __builtin_amdgcn_mfma_f32_16x16x32_bf16(a1_, bw_, acc1, 0, 0, 0); \
        }                                                                       \
    } while (0)

    const int n = (kg < 12) ? 33 : 32;           // chunks owned: kg + t*128 < 4108
    int c = kg;

    WSTAGE(0, c);                                // 8 DMA
    WSTAGE(1, c + KGN);                          // 16 in flight
    FCOMP(0, c);
    FCOMP(1, c + KGN);

    for (int t = 0; t < n; ++t) {
        if (t < n - 1)
            asm volatile("s_waitcnt vmcnt(8) lgkmcnt(0)" ::: "memory");
        else
            asm volatile("s_waitcnt vmcnt(0) lgkmcnt(0)" ::: "memory");
        __builtin_amdgcn_s_barrier();            // all waves' chunk-t data in LDS
        COMPUTE(t & 1);
        __builtin_amdgcn_s_barrier();            // all waves done reading buf[t&1]
        if (t + 2 < n) {
            WSTAGE(t & 1, c + 2 * KGN);          // overwrite with chunk t+2
            FCOMP(t & 1, c + 2 * KGN);
        }
        c += KGN;
    }

    #undef COMPUTE
    #undef FCOMP
    #undef WSTAGE

    // C layout: C[b = (lane>>4)*4 + reg][o = lane&15]; plain stores to partial[kg]
    float* pb = partial + (size_t)kg * (B_SZ * OUT_DIM) + o_base + lrow;
    const int r0 = lkb * 4;
    #pragma unroll
    for (int r = 0; r < 4; ++r) {
        pb[(size_t)(r0 + r) * OUT_DIM]      = acc0[r];
        pb[(size_t)(16 + r0 + r) * OUT_DIM] = acc1[r];
    }
}

// ------------- kernel C: reduce 128 partials + bias -> out
__global__ __launch_bounds__(256)
void reduce_kernel(const float* __restrict__ partial,
                   const float* __restrict__ bias,
                   float* __restrict__ out)
{
    const int idx = blockIdx.x * 256 + threadIdx.x;   // 0..16383
    float s = bias[idx & (OUT_DIM - 1)];
    const float* p = partial + idx;
    #pragma unroll 8
    for (int kg = 0; kg < KGN; ++kg)
        s += p[(size_t)kg * (B_SZ * OUT_DIM)];
    out[idx] = s;
}

// ------------------------------------------------- fallback (proven v2 path)
__global__ __launch_bounds__(512, 2)
void qgemm_fallback_kernel(const float* __restrict__ x,
                           const float* __restrict__ W,
                           float* __restrict__ out)
{
    __shared__ float xt[B_SZ][512];

    const int tid  = threadIdx.x;
    const int lane = tid & 63;
    const int wave = tid >> 6;
    const int bgrp = wave & 3;
    const int ogrp = wave >> 2;

    const int og  = blockIdx.x & 31;
    const int kgf = blockIdx.x >> 5;

    const int o_base = og * 16 + ogrp * 8;
    const int b_base = bgrp * 8;

    float acc[8][8];
    #pragma unroll
    for (int i = 0; i < 8; ++i)
        #pragma unroll
        for (int o = 0; o < 8; ++o) acc[i][o] = 0.f;

    const int nch = (K_TOTAL + 511) / 512;
    for (int chunk = kgf; chunk < nch; chunk += 16) {
        const int k = chunk * 512 + tid;
        __syncthreads();
        if (k < IN_DIM) {
            #pragma unroll
            for (int b = 0; b < B_SZ; ++b)
                xt[b][tid] = x[b * IN_DIM + k];
        } else {
            const int t = k - IN_DIM;
            double disc = 4198401.0 - 8.0 * (double)t;
            int r = (int)((2049.0 - sqrt(disc)) * 0.5);
            int off = r * IN_DIM - ((r * (r - 1)) >> 1);
            if (t < off) { --r; off = r * IN_DIM - ((r * (r - 1)) >> 1); }
            else if (t >= off + (IN_DIM - r)) { off += IN_DIM - r; ++r; }
            const int ccol = r + (t - off);
            #pragma unroll
            for (int b = 0; b < B_SZ; ++b)
                xt[b][tid] = x[b * IN_DIM + r] * x[b * IN_DIM + ccol];
        }
        __syncthreads();

        const float* wrow = W + (size_t)o_base * K_TOTAL + (size_t)chunk * 512;
        #pragma unroll
        for (int pass = 0; pass < 2; ++pass) {
            const int kk = pass * 256 + lane * 4;
            float4 wv[8];
            #pragma unroll
            for (int o = 0; o < 8; ++o)
                wv[o] = *(const float4*)(wrow + (size_t)o * K_TOTAL + kk);
            float4 xv[8];
            #pragma unroll
            for (int i = 0; i < 8; ++i)
                xv[i] = *(const float4*)&xt[b_base + i][kk];
            #pragma unroll
            for (int o = 0; o < 8; ++o)
                #pragma unroll
                for (int i = 0; i < 8; ++i)
                    acc[i][o] += xv[i].x * wv[o].x + xv[i].y * wv[o].y
                               + xv[i].z * wv[o].z + xv[i].w * wv[o].w;
        }
    }

    #pragma unroll
    for (int i = 0; i < 8; ++i)
        #pragma unroll
        for (int o = 0; o < 8; ++o) {
            float v = acc[i][o];
            #pragma unroll
            for (int m = 1; m < 64; m <<= 1)
                v += __shfl_xor(v, m);
            acc[i][o] = v;
        }

    if (lane == 0) {
        #pragma unroll
        for (int i = 0; i < 8; ++i)
            #pragma unroll
            for (int o = 0; o < 8; ++o)
                atomicAdd(&out[(b_base + i) * OUT_DIM + o_base + o], acc[i][o]);
    }
}

extern "C" void kernel_launch(void* const* d_in, const int* in_sizes, int n_in,
                              void* d_out, int out_size, void* d_ws, size_t ws_size,
                              hipStream_t stream)
{
    const float* x    = (const float*)d_in[0];   // [32,1024] fp32
    const float* W    = (const float*)d_in[1];   // [512, 525824] fp32
    const float* bias = (const float*)d_in[2];   // [512] fp32
    float* out = (float*)d_out;                  // [32,512] fp32

    if (ws_size >= NEED_WS) {
        float* part = (float*)d_ws;
        float* xT   = (float*)((char*)d_ws + P_BYTES);
        hipLaunchKernelGGL(xpose_kernel, dim3(128), dim3(256), 0, stream, x, xT);
        hipLaunchKernelGGL(qgemm_mfma_kernel, dim3(8 * KGN), dim3(256), 0, stream,
                           xT, W, part);
        hipLaunchKernelGGL(reduce_kernel, dim3(64), dim3(256), 0, stream,
                           part, bias, out);
    } else {
        hipLaunchKernelGGL(bias_init_kernel, dim3(64), dim3(256), 0, stream, bias, out);
        hipLaunchKernelGGL(qgemm_fallback_kernel, dim3(512), dim3(512), 0, stream,
                           x, W, out);
    }
}